// Round 5
// baseline (200.414 us; speedup 1.0000x reference)
//
#include <hip/hip_runtime.h>
#include <stdint.h>
#include <stddef.h>

#define SS 4096
#define DD 64
#define TK 64
#define LOG2E 1.4426950408889634f
#define NEG_M_L2 (-57.70780163555854f)   /* -40 * log2(e), fixed softmax shift */

typedef short    short4v __attribute__((ext_vector_type(4)));
typedef short    short8 __attribute__((ext_vector_type(8)));
typedef _Float16 half8  __attribute__((ext_vector_type(8)));
typedef float    f32x4  __attribute__((ext_vector_type(4)));
typedef __bf16   bf16x8v __attribute__((ext_vector_type(8)));
typedef __bf16   bf16x8 __attribute__((ext_vector_type(8)));

typedef __attribute__((address_space(1))) void void_g;
typedef __attribute__((address_space(3))) void void_l;

static __device__ __forceinline__ void gl_lds16(const void* g, void* l) {
    __builtin_amdgcn_global_load_lds((void_g*)(g), (void_l*)(l), 16, 0, 0);
}

#define MFMA_F16(A, B, C) __builtin_amdgcn_mfma_f32_16x16x32_f16( \
    __builtin_bit_cast(half8, A), __builtin_bit_cast(half8, B), (C), 0, 0, 0)
#define MFMA_BF16(A, B, C) __builtin_amdgcn_mfma_f32_16x16x32_bf16( \
    __builtin_bit_cast(bf16x8, A), __builtin_bit_cast(bf16x8, B), (C), 0, 0, 0)

// ---------------- fused prep: f16 row-major (QK^T operands) + bf16 V^T.
// f16 path is PURE STREAMING (no LDS round-trip): read 32B of f32, cvt, store
// rotated 16B group. Only the bf16 transpose uses the LDS fp32 tile
// (stride 69 floats; 69%4==1 -> scalar gathers <=2-way = free).
// f16 rows: groups rotated by ((g + r + 2*((r>>3)&3)) & 7) (matches biattn's
// permuted K-row reads, 2-way max). V^T groups rotated by ((k8+d)&7).
__global__ __launch_bounds__(256) void prep(
    const float* __restrict__ x, const float* __restrict__ y,
    _Float16* __restrict__ fx, _Float16* __restrict__ fy,
    unsigned short* __restrict__ tx, unsigned short* __restrict__ ty) {
    __shared__ float tile[64 * 69];
    int bid = blockIdx.x;                       // 1024 = 2 mats x 8 b x 64 tiles
    int mat = bid >> 9;
    int rem = bid & 511;
    int b = rem >> 6, t64 = rem & 63;
    int s0 = t64 * 64;
    const float* src = (mat ? y : x) + ((size_t)b * SS + s0) * 64;
    _Float16* fr = (mat ? fy : fx) + ((size_t)b * SS + s0) * 64;
    unsigned short* tr = (mat ? ty : tx) + (size_t)b * SS * 64;
    int tid = threadIdx.x;
    // stage fp32 tile (for the transpose path)
#pragma unroll
    for (int it = 0; it < 4; ++it) {
        int qi = it * 256 + tid;
        int r = qi >> 4, c4 = (qi & 15) * 4;
        f32x4 v = *(const f32x4*)(src + r * 64 + c4);
#pragma unroll
        for (int j = 0; j < 4; ++j) tile[r * 69 + c4 + j] = v[j];
    }
    // streaming f16 row-major (L2-hot re-read; no LDS dependency)
#pragma unroll
    for (int j2 = 0; j2 < 2; ++j2) {
        int seg = j2 * 256 + tid;               // 512 groups
        int r = seg >> 3, g = seg & 7;
        const float* sp8 = src + r * 64 + g * 8;
        f32x4 v0 = *(const f32x4*)(sp8);
        f32x4 v1 = *(const f32x4*)(sp8 + 4);
        half8 h;
#pragma unroll
        for (int j = 0; j < 4; ++j) { h[j] = (_Float16)v0[j]; h[4 + j] = (_Float16)v1[j]; }
        *(half8*)(fr + (size_t)r * 64 + ((g + r + 2 * ((r >> 3) & 3)) & 7) * 8) = h;
    }
    __syncthreads();
    // transposed bf16 [d][4096]
#pragma unroll
    for (int j2 = 0; j2 < 2; ++j2) {
        int seg = j2 * 256 + tid;
        int d = seg >> 3, k8 = seg & 7;
        bf16x8v h;
#pragma unroll
        for (int i = 0; i < 8; ++i)
            h[i] = (__bf16)tile[(k8 * 8 + i) * 69 + d];
        *(short8*)(tr + (size_t)d * SS + s0 + ((k8 + d) & 7) * 8) =
            __builtin_bit_cast(short8, h);
    }
}

// ---------------- main flash kernel (R5: 1-step software pipeline)
// R4 diagnosis: residency pins ~3 blocks/CU regardless of grid; wall 84us vs
// 37us MFMA-pipe / ~40us VALU-pipe => ~50% intra-wave dependency stall from
// the serial chain (barrier; ds_read -> QK -> exp -> cvt -> PV) x2 barriers.
// Fix: carry sacc one K-step so each iteration runs THREE independent streams
//   QK-MFMA(t)  ||  exp/cvt-VALU(t-1)  ||  PV-MFMA(t-1)
// Needs tile t-1 V resident while tile t+1 DMAs -> 3-buffer LDS (48KB,
// 3 blocks/CU = observed residency cap), ONE barrier per K-step, issue-early
// DMA (a full step in flight before its vmcnt drain). Denominator moved off
// the MFMA pipe (was 4 ones-MFMA/step) to 32 VALU adds + end shfl_xor reduce.
__global__ __launch_bounds__(256, 3)
void biattn(const float* __restrict__ xg, const float* __restrict__ yg,
            const _Float16* __restrict__ fx, const _Float16* __restrict__ fy,
            const unsigned short* __restrict__ tx, const unsigned short* __restrict__ ty,
            float* __restrict__ wsO, float* __restrict__ wsL,
            float* __restrict__ out, int nsplit, int kcount) {
    __shared__ _Float16 shK3[3][TK * DD];       // 3 x 8 KB, rotated rows
    __shared__ unsigned short shV3[3][DD * TK]; // 3 x 8 KB, [d][k] rotated

    const int bid = blockIdx.x;                 // nsplit*512 blocks
    const int sp = bid >> 9;                    // split index
    const int r = bid & 511;
    const int bd = (r & 7) | ((r >> 8) << 3);   // low bits -> XCD spread
    const int qb = (r >> 3) & 31;
    const int b = bd >> 1, dir = bd & 1;
    const size_t mo = (size_t)b * SS * DD;
    const _Float16* Kf = (dir ? fx : fy) + mo;
    const unsigned short* Vt = (dir ? tx : ty) + mo;
    const _Float16* Qf = (dir ? fy : fx) + mo;
    const float* Qm = (dir ? yg : xg) + mo;

    const int tid = threadIdx.x, w = tid >> 6, ln = tid & 63;
    const int l15 = ln & 15, quad = ln >> 4;
    const int q0 = qb * 128 + w * 32;

    // Q fragments f16 (B-operand: lane holds Q[q=l15+16qs][d=c*32+quad*8+j])
    half8 qf[2][2];
#pragma unroll
    for (int qs = 0; qs < 2; ++qs) {
        int qrow = q0 + qs * 16 + l15;
#pragma unroll
        for (int c = 0; c < 2; ++c)
            qf[qs][c] = *(const half8*)(Qf + (size_t)qrow * 64 +
                ((c * 4 + quad + qrow + 2 * ((qrow >> 3) & 3)) & 7) * 8);
    }

    // Permuted K-row offsets: st0 reads shK rows (l15>>2)*8+(l15&3), st1 +4
    // => lane quad's C rows = keys quad*8+st*4+j (PV B-frag is lane-local).
    int koff[2][2][2];
#pragma unroll
    for (int c32 = 0; c32 < 2; ++c32)
#pragma unroll
        for (int st = 0; st < 2; ++st) {
            int kl = c32 * 32 + (l15 >> 2) * 8 + (l15 & 3) + st * 4;
            int rot = kl + 2 * ((kl >> 3) & 3);
#pragma unroll
            for (int c = 0; c < 2; ++c)
                koff[c32][st][c] = kl * 64 + ((c * 4 + quad + rot) & 7) * 8;
        }

    f32x4 Oa[2][4];
#pragma unroll
    for (int qs = 0; qs < 2; ++qs)
#pragma unroll
        for (int dt = 0; dt < 4; ++dt) Oa[qs][dt] = (f32x4){0.f, 0.f, 0.f, 0.f};
    float Lp[2] = {0.f, 0.f};
    const f32x4 zero4 = (f32x4){0.f, 0.f, 0.f, 0.f};

    const int kblo = sp * kcount;
    const int nsteps = kcount / TK;             // >= 16

#define STAGE(BUF, KB) do {                                                   \
    _Float16* dK_ = &shK3[(BUF)][0];                                          \
    unsigned short* dV_ = &shV3[(BUF)][0];                                    \
    _Pragma("unroll")                                                         \
    for (int i_ = 0; i_ < 4; ++i_) {                                          \
        int seg_ = w * 4 + i_;                                                \
        if (seg_ < 8) {                                                       \
            gl_lds16(Kf + (size_t)(KB) * 64 + seg_ * 512 + ln * 8,            \
                     (void*)(dK_ + seg_ * 512));                              \
        } else {                                                              \
            int s2_ = seg_ - 8;                                               \
            int d_ = s2_ * 8 + (ln >> 3);                                     \
            gl_lds16(Vt + (size_t)d_ * SS + (KB) + (ln & 7) * 8,              \
                     (void*)(dV_ + s2_ * 512));                               \
        }                                                                     \
    } } while (0)

#define QK_ALL(IBUF, SAC) do {                                                \
    const _Float16* Kb_ = &shK3[(IBUF)][0];                                   \
    _Pragma("unroll")                                                         \
    for (int c32_ = 0; c32_ < 2; ++c32_)                                      \
    _Pragma("unroll")                                                         \
    for (int st_ = 0; st_ < 2; ++st_) {                                       \
        half8 a0_ = *(const half8*)(Kb_ + koff[c32_][st_][0]);                \
        half8 a1_ = *(const half8*)(Kb_ + koff[c32_][st_][1]);                \
        _Pragma("unroll")                                                     \
        for (int qs_ = 0; qs_ < 2; ++qs_) {                                   \
            f32x4 acc_ = MFMA_F16(a0_, qf[qs_][0], zero4);                    \
            acc_ = MFMA_F16(a1_, qf[qs_][1], acc_);                           \
            SAC[qs_][c32_][st_] = acc_;                                       \
        }                                                                     \
    } } while (0)

#define EXP_ALL(SAC, BFR) do {                                                \
    _Pragma("unroll")                                                         \
    for (int qs_ = 0; qs_ < 2; ++qs_)                                         \
    _Pragma("unroll")                                                         \
    for (int c32_ = 0; c32_ < 2; ++c32_) {                                    \
        bf16x8v pk_;                                                          \
        _Pragma("unroll")                                                     \
        for (int st_ = 0; st_ < 2; ++st_) {                                   \
            f32x4 sv_ = SAC[qs_][c32_][st_];                                  \
            float p0_ = __builtin_amdgcn_exp2f(__builtin_fmaf(sv_[0], LOG2E, NEG_M_L2)); \
            float p1_ = __builtin_amdgcn_exp2f(__builtin_fmaf(sv_[1], LOG2E, NEG_M_L2)); \
            float p2_ = __builtin_amdgcn_exp2f(__builtin_fmaf(sv_[2], LOG2E, NEG_M_L2)); \
            float p3_ = __builtin_amdgcn_exp2f(__builtin_fmaf(sv_[3], LOG2E, NEG_M_L2)); \
            pk_[st_ * 4 + 0] = (__bf16)p0_;                                   \
            pk_[st_ * 4 + 1] = (__bf16)p1_;                                   \
            pk_[st_ * 4 + 2] = (__bf16)p2_;                                   \
            pk_[st_ * 4 + 3] = (__bf16)p3_;                                   \
            Lp[qs_] += ((p0_ + p1_) + (p2_ + p3_));                           \
        }                                                                     \
        BFR[qs_][c32_] = __builtin_bit_cast(short8, pk_);                     \
    } } while (0)

#define PV_ALL(IBUF, BFR) do {                                                \
    const unsigned short* Vb_ = &shV3[(IBUF)][0];                             \
    _Pragma("unroll")                                                         \
    for (int c32_ = 0; c32_ < 2; ++c32_) {                                    \
        const int rotv_ = ((c32_ * 4 + quad + l15) & 7) * 8;                  \
        _Pragma("unroll")                                                     \
        for (int dt_ = 0; dt_ < 4; ++dt_) {                                   \
            short8 av_ = *(const short8*)(Vb_ + (dt_ * 16 + l15) * 64 + rotv_); \
            Oa[0][dt_] = MFMA_BF16(av_, BFR[0][c32_], Oa[0][dt_]);            \
            Oa[1][dt_] = MFMA_BF16(av_, BFR[1][c32_], Oa[1][dt_]);            \
        }                                                                     \
    } } while (0)

#define ITER(T, SPRV, SNEW) do {                                              \
    __syncthreads();            /* DMA(tile T) drained; PV(T-2) done by all */ \
    if ((T) + 1 < nsteps) STAGE(in_, kblo + ((T) + 1) * TK);                  \
    short8 bfr_[2][2];                                                        \
    EXP_ALL(SPRV, bfr_);        /* VALU stream, indep of QK below */          \
    QK_ALL(ic, SNEW);           /* MFMA stream on tile T */                   \
    PV_ALL(ip, bfr_);           /* MFMA stream on tile T-1 */                 \
    int tmp_ = ip; ip = ic; ic = in_; in_ = tmp_;                             \
    } while (0)

    // prologue
    STAGE(0, kblo);
    __syncthreads();                            // tile 0 resident
    STAGE(1, kblo + TK);                        // in flight across QK(0)
    f32x4 sp_[2][2][2], sn_[2][2][2];
    QK_ALL(0, sp_);
    int ip = 0, ic = 1, in_ = 2;

    int t = 1;
    for (; t + 1 < nsteps; t += 2) {
        ITER(t, sp_, sn_);
        ITER(t + 1, sn_, sp_);
    }
    short8 bfrF[2][2];
    if (t < nsteps) {                           // even nsteps: one leftover
        ITER(t, sp_, sn_);
        EXP_ALL(sn_, bfrF);
    } else {
        EXP_ALL(sp_, bfrF);
    }
    PV_ALL(ip, bfrF);                           // last tile's buffer = ip

    // denominator: lane-local 16-key partials -> sum over quad groups
    float lq[2];
#pragma unroll
    for (int qs = 0; qs < 2; ++qs) {
        float v = Lp[qs];
        v += __shfl_xor(v, 16);
        v += __shfl_xor(v, 32);
        lq[qs] = v;
    }

    if (nsplit > 1) {
        const int ps = sp * 512 + bd * 32 + qb;
#pragma unroll
        for (int qs = 0; qs < 2; ++qs) {
            float* base = wsO + (size_t)ps * 8192 + (size_t)(w * 2 + qs) * 1024
                        + l15 * 16 + quad * 4;
#pragma unroll
            for (int dt = 0; dt < 4; ++dt)
                *(f32x4*)(base + dt * 256) = Oa[qs][dt];
            if (quad == 0)
                wsL[(size_t)ps * 128 + w * 32 + qs * 16 + l15] = lq[qs];
        }
    } else {
        // direct epilogue: a = (O^T / l) * Qrow
#pragma unroll
        for (int qs = 0; qs < 2; ++qs) {
            float inv = 1.0f / lq[qs];
            int qrow = q0 + qs * 16 + l15;
#pragma unroll
            for (int dt = 0; dt < 4; ++dt) {
                const float* qp = Qm + (size_t)qrow * DD + dt * 16 + quad * 4;
                f32x4 xv = *(const f32x4*)qp;
                f32x4 o = Oa[qs][dt];
                f32x4 rr;
#pragma unroll
                for (int j = 0; j < 4; ++j) rr[j] = o[j] * inv * xv[j];
                float* op = out + ((size_t)(b * SS + qrow)) * 128 + dir * 64
                          + dt * 16 + quad * 4;
                *(f32x4*)op = rr;
            }
        }
    }
#undef STAGE
#undef QK_ALL
#undef EXP_ALL
#undef PV_ALL
#undef ITER
}

// ---------------- split-K combine: out = (sum_sp O_sp)/(sum_sp l_sp) * Q
__global__ __launch_bounds__(256) void combine(
    const float* __restrict__ xg, const float* __restrict__ yg,
    const float* __restrict__ wsO, const float* __restrict__ wsL,
    float* __restrict__ out, int nsplit) {
    __shared__ float t[8 * 1088];               // seg stride 1088, d stride 17
    int pb = blockIdx.x;                        // 512 = bd*32 + qb
    int bd = pb >> 5, qb = pb & 31;
    int b = bd >> 1, dir = bd & 1;
    const float* Qm = (dir ? yg : xg) + (size_t)b * SS * DD;
    int tid = threadIdx.x;
#pragma unroll
    for (int j = 0; j < 8; ++j) {
        int idx = j * 1024 + tid * 4;           // sub == j for all threads
        f32x4 a = *(const f32x4*)(wsO + (size_t)pb * 8192 + idx);
        for (int s2 = 1; s2 < nsplit; ++s2) {
            f32x4 c = *(const f32x4*)(wsO + (size_t)(s2 * 512 + pb) * 8192 + idx);
#pragma unroll
            for (int jj = 0; jj < 4; ++jj) a[jj] += c[jj];
        }
        int dt = (idx >> 8) & 3, q = (idx >> 4) & 15, dq = idx & 15;
#pragma unroll
        for (int jj = 0; jj < 4; ++jj)
            t[j * 1088 + (dt * 16 + dq + jj) * 17 + q] = a[jj];
    }
    __syncthreads();
    int w2 = tid >> 6, ln = tid & 63;
    int q00 = qb * 128;
#pragma unroll 4
    for (int i = 0; i < 32; ++i) {
        int q128 = w2 * 32 + i;
        int seg = q128 >> 4, lq = q128 & 15;
        float o = t[seg * 1088 + ln * 17 + lq];
        float l = wsL[(size_t)pb * 128 + q128];
        for (int s2 = 1; s2 < nsplit; ++s2)
            l += wsL[(size_t)(s2 * 512 + pb) * 128 + q128];
        float qv = Qm[(size_t)(q00 + q128) * 64 + ln];
        out[((size_t)(b * SS + q00 + q128)) * 128 + dir * 64 + ln]
            = o * (1.0f / l) * qv;
    }
}

extern "C" void kernel_launch(void* const* d_in, const int* in_sizes, int n_in,
                              void* d_out, int out_size, void* d_ws, size_t ws_size,
                              hipStream_t stream) {
    const float* x = (const float*)d_in[0];
    const float* y = (const float*)d_in[1];
    char* ws = (char*)d_ws;
    const size_t MATB = (size_t)8 * SS * DD * 2;        // 4 MiB per f16/bf16 copy
    const size_t OSET = (size_t)512 * 8192 * 4;         // 16.78 MB per split
    const size_t LSET = (size_t)512 * 128 * 4;          // 0.26 MB per split
    _Float16* fx = (_Float16*)(ws);
    _Float16* fy = (_Float16*)(ws + MATB);
    unsigned short* tx = (unsigned short*)(ws + 2 * MATB);
    unsigned short* ty = (unsigned short*)(ws + 3 * MATB);
    int nsplit = 1;
    if (ws_size >= 4 * MATB + 2 * (OSET + LSET)) nsplit = 2;  // 2 splits: less
    float* wsO = (float*)(ws + 4 * MATB);                     // combine traffic
    float* wsL = (float*)(ws + 4 * MATB + (size_t)nsplit * OSET);
    (void)in_sizes; (void)n_in; (void)out_size;
    prep<<<dim3(1024), dim3(256), 0, stream>>>(x, y, fx, fy, tx, ty);
    biattn<<<dim3(nsplit * 512), dim3(256), 0, stream>>>(
        x, y, fx, fy, tx, ty, wsO, wsL, (float*)d_out, nsplit, SS / nsplit);
    if (nsplit > 1)
        combine<<<dim3(512), dim3(256), 0, stream>>>(
            x, y, wsO, wsL, (float*)d_out, nsplit);
}

// Round 7
// 163.471 us; speedup vs baseline: 1.2260x; 1.2260x over previous
//
#include <hip/hip_runtime.h>
#include <stdint.h>
#include <stddef.h>

#define SS 4096
#define DD 64
#define TK 64
#define LOG2E 1.4426950408889634f
#define NEG_M_L2 (-57.70780163555854f)   /* -40 * log2(e), fixed softmax shift */

typedef short    short8 __attribute__((ext_vector_type(8)));
typedef _Float16 half8  __attribute__((ext_vector_type(8)));
typedef float    f32x4  __attribute__((ext_vector_type(4)));
typedef __bf16   bf16x8v __attribute__((ext_vector_type(8)));
typedef __bf16   bf16x8 __attribute__((ext_vector_type(8)));

typedef __attribute__((address_space(1))) void void_g;
typedef __attribute__((address_space(3))) void void_l;

static __device__ __forceinline__ void gl_lds16(const void* g, void* l) {
    __builtin_amdgcn_global_load_lds((void_g*)(g), (void_l*)(l), 16, 0, 0);
}

#define MFMA_F16(A, B, C) __builtin_amdgcn_mfma_f32_16x16x32_f16( \
    __builtin_bit_cast(half8, A), __builtin_bit_cast(half8, B), (C), 0, 0, 0)
#define MFMA_BF16(A, B, C) __builtin_amdgcn_mfma_f32_16x16x32_bf16( \
    __builtin_bit_cast(bf16x8, A), __builtin_bit_cast(bf16x8, B), (C), 0, 0, 0)

// ---------------- fused prep: f16 row-major (QK^T operands) + bf16 V^T.
// f16 path is pure streaming (no LDS round-trip). bf16 transpose gathers from
// the fp32 LDS tile (stride 69; 69%4==1 -> <=2-way = free).
// f16 rows: groups rotated by ((g + r + 2*((r>>3)&3)) & 7) (matches biattn's
// permuted K-row reads, 2-way max). V^T groups rotated by ((k8+d)&7).
__global__ __launch_bounds__(256) void prep(
    const float* __restrict__ x, const float* __restrict__ y,
    _Float16* __restrict__ fx, _Float16* __restrict__ fy,
    unsigned short* __restrict__ tx, unsigned short* __restrict__ ty) {
    __shared__ float tile[64 * 69];
    int bid = blockIdx.x;                       // 1024 = 2 mats x 8 b x 64 tiles
    int mat = bid >> 9;
    int rem = bid & 511;
    int b = rem >> 6, t64 = rem & 63;
    int s0 = t64 * 64;
    const float* src = (mat ? y : x) + ((size_t)b * SS + s0) * 64;
    _Float16* fr = (mat ? fy : fx) + ((size_t)b * SS + s0) * 64;
    unsigned short* tr = (mat ? ty : tx) + (size_t)b * SS * 64;
    int tid = threadIdx.x;
#pragma unroll
    for (int it = 0; it < 4; ++it) {
        int qi = it * 256 + tid;
        int r = qi >> 4, c4 = (qi & 15) * 4;
        f32x4 v = *(const f32x4*)(src + r * 64 + c4);
#pragma unroll
        for (int j = 0; j < 4; ++j) tile[r * 69 + c4 + j] = v[j];
    }
#pragma unroll
    for (int j2 = 0; j2 < 2; ++j2) {
        int seg = j2 * 256 + tid;               // 512 groups
        int r = seg >> 3, g = seg & 7;
        const float* sp8 = src + r * 64 + g * 8;
        f32x4 v0 = *(const f32x4*)(sp8);
        f32x4 v1 = *(const f32x4*)(sp8 + 4);
        half8 h;
#pragma unroll
        for (int j = 0; j < 4; ++j) { h[j] = (_Float16)v0[j]; h[4 + j] = (_Float16)v1[j]; }
        *(half8*)(fr + (size_t)r * 64 + ((g + r + 2 * ((r >> 3) & 3)) & 7) * 8) = h;
    }
    __syncthreads();
#pragma unroll
    for (int j2 = 0; j2 < 2; ++j2) {
        int seg = j2 * 256 + tid;
        int d = seg >> 3, k8 = seg & 7;
        bf16x8v h;
#pragma unroll
        for (int i = 0; i < 8; ++i)
            h[i] = (__bf16)tile[(k8 * 8 + i) * 69 + d];
        *(short8*)(tr + (size_t)d * SS + s0 + ((k8 + d) & 7) * 8) =
            __builtin_bit_cast(short8, h);
    }
}

// ---------------- main flash kernel (R6: light waves, exact-fit residency)
// R5 post-mortem: 3-buf pipeline cut residency (23% occ) and raised VGPR ->
// slower. Lever is TLP, not per-wave ILP. R6: 16 q-rows per wave (qs dim
// dropped; all layout math identical), nsplit=1:
//   grid = 16 bd x 64 q-tiles = 1024 blocks = EXACTLY 4 blocks/CU, all
//   co-resident (no tail), 16 waves/CU. LDS = proven 32KB dbuf (4x32=128KB).
//   VGPR ~60-70 (cap 128 via launch_bounds(256,4)) -> no spill.
// No split => exact denominator, direct epilogue, no wsO/wsL, no combine.
// One barrier per K-step, issue-early DMA (R2's verified pattern).
// bd = bid&15 -> XCD i serves bd {i, i+8}: 2MB K/V hot in its 4MB L2.
__global__ __launch_bounds__(256, 4)
void biattn(const float* __restrict__ xg, const float* __restrict__ yg,
            const _Float16* __restrict__ fx, const _Float16* __restrict__ fy,
            const unsigned short* __restrict__ tx, const unsigned short* __restrict__ ty,
            float* __restrict__ out) {
    __shared__ _Float16 shK[2][TK * DD];        // 2 x 8 KB, rotated rows
    __shared__ unsigned short shVt[2][DD * TK]; // 2 x 8 KB, [d][k] rotated

    const int bid = blockIdx.x;                 // 1024
    const int bd = bid & 15, qt = bid >> 4;     // bd -> XCD by low 3 bits
    const int b = bd >> 1, dir = bd & 1;
    const size_t mo = (size_t)b * SS * DD;
    const _Float16* Kf = (dir ? fx : fy) + mo;
    const unsigned short* Vt = (dir ? tx : ty) + mo;
    const _Float16* Qf = (dir ? fy : fx) + mo;
    const float* Qm = (dir ? yg : xg) + mo;

    const int tid = threadIdx.x, w = tid >> 6, ln = tid & 63;
    const int l15 = ln & 15, quad = ln >> 4;
    const int q0 = qt * 64 + w * 16;            // 16 q-rows per wave
    const int qrow = q0 + l15;

    // Q fragment f16 (B-operand: lane holds Q[q=l15][d=c*32+quad*8+j])
    half8 qf[2];
#pragma unroll
    for (int c = 0; c < 2; ++c)
        qf[c] = *(const half8*)(Qf + (size_t)qrow * 64 +
            ((c * 4 + quad + qrow + 2 * ((qrow >> 3) & 3)) & 7) * 8);

    // Permuted K-row offsets: st0 reads shK rows (l15>>2)*8+(l15&3), st1 +4
    // => lane quad's C rows = keys c32*32 + quad*8 + st*4 + j
    // (PV B-fragment keys quad*8+0..7 are lane-local after exp).
    int koff[2][2][2];
#pragma unroll
    for (int c32 = 0; c32 < 2; ++c32)
#pragma unroll
        for (int st = 0; st < 2; ++st) {
            int kl = c32 * 32 + (l15 >> 2) * 8 + (l15 & 3) + st * 4;
            int rot = kl + 2 * ((kl >> 3) & 3);
#pragma unroll
            for (int c = 0; c < 2; ++c)
                koff[c32][st][c] = kl * 64 + ((c * 4 + quad + rot) & 7) * 8;
        }
    // V^T read offsets (loop-invariant): group g=c32*4+quad of row dt*16+l15
    int rotv[2];
#pragma unroll
    for (int c32 = 0; c32 < 2; ++c32)
        rotv[c32] = ((c32 * 4 + quad + l15) & 7) * 8;

    const f32x4 zero4 = {0.f, 0.f, 0.f, 0.f};
    f32x4 Oa[4], La;
#pragma unroll
    for (int dt = 0; dt < 4; ++dt) Oa[dt] = zero4;
    La = zero4;
    short8 onesb;
#pragma unroll
    for (int j = 0; j < 8; ++j) onesb[j] = (short)0x3F80;  // bf16 1.0

#define STAGE(BUF, KB) do {                                                   \
    _Pragma("unroll")                                                         \
    for (int i_ = 0; i_ < 4; ++i_) {                                          \
        int seg_ = w * 4 + i_;               /* 16 segs of 1KB */             \
        if (seg_ < 8) {                                                       \
            gl_lds16(Kf + (size_t)(KB) * 64 + seg_ * 512 + ln * 8,            \
                     (void*)(&shK[(BUF)][0] + seg_ * 512));                   \
        } else {                                                              \
            int s2_ = seg_ - 8;                                               \
            int d_ = s2_ * 8 + (ln >> 3);                                     \
            gl_lds16(Vt + (size_t)d_ * SS + (KB) + (ln & 7) * 8,              \
                     (void*)(&shVt[(BUF)][0] + s2_ * 512));                   \
        }                                                                     \
    } } while (0)

    STAGE(0, 0);
    __syncthreads();                            // tile 0 resident

    int buf = 0;
    for (int t = 0; t < SS / TK; ++t) {
        const int more = (t + 1 < SS / TK);
        if (more) STAGE(buf ^ 1, (t + 1) * TK); // in flight across this step
        const _Float16* Kb = &shK[buf][0];
        const unsigned short* Vb = &shVt[buf][0];

#pragma unroll
        for (int c32 = 0; c32 < 2; ++c32) {
            // ---- QK^T f16: S[key = c32*32+quad*8+st*4+j][q=l15] ----
            f32x4 sacc[2];
#pragma unroll
            for (int st = 0; st < 2; ++st) {
                half8 a0 = *(const half8*)(Kb + koff[c32][st][0]);
                half8 a1 = *(const half8*)(Kb + koff[c32][st][1]);
                f32x4 acc = MFMA_F16(a0, qf[0], zero4);
                sacc[st] = MFMA_F16(a1, qf[1], acc);
            }
            // ---- fixed-shift softmax numerator, packed in registers ----
            bf16x8v pk;
#pragma unroll
            for (int st = 0; st < 2; ++st)
#pragma unroll
                for (int j = 0; j < 4; ++j) {
                    float p = __builtin_amdgcn_exp2f(
                        __builtin_fmaf(sacc[st][j], LOG2E, NEG_M_L2));
                    pk[st * 4 + j] = (__bf16)p;
                }
            short8 bfr = __builtin_bit_cast(short8, pk);
            // ---- PV bf16: O^T += V^T . P^T ; La += ones . P^T ----
#pragma unroll
            for (int dt = 0; dt < 4; ++dt) {
                short8 av = *(const short8*)(Vb + (dt * 16 + l15) * 64 + rotv[c32]);
                Oa[dt] = MFMA_BF16(av, bfr, Oa[dt]);
            }
            La = MFMA_BF16(onesb, bfr, La);
        }

        if (more) __syncthreads();  // WAR on buf + RAW drain for buf^1 DMA
        buf ^= 1;
    }
#undef STAGE

    // direct epilogue: a = (O^T / l) * Qrow   (exact denominator, no split)
    {
        float inv = 1.0f / La[0];
#pragma unroll
        for (int dt = 0; dt < 4; ++dt) {
            const float* qp = Qm + (size_t)qrow * DD + dt * 16 + quad * 4;
            f32x4 xv = *(const f32x4*)qp;
            f32x4 o = Oa[dt];
            f32x4 rr;
#pragma unroll
            for (int j = 0; j < 4; ++j) rr[j] = o[j] * inv * xv[j];
            float* op = out + ((size_t)(b * SS + qrow)) * 128 + dir * 64
                      + dt * 16 + quad * 4;
            *(f32x4*)op = rr;
        }
    }
}

extern "C" void kernel_launch(void* const* d_in, const int* in_sizes, int n_in,
                              void* d_out, int out_size, void* d_ws, size_t ws_size,
                              hipStream_t stream) {
    const float* x = (const float*)d_in[0];
    const float* y = (const float*)d_in[1];
    char* ws = (char*)d_ws;
    const size_t MATB = (size_t)8 * SS * DD * 2;        // 4 MiB per f16/bf16 copy
    _Float16* fx = (_Float16*)(ws);
    _Float16* fy = (_Float16*)(ws + MATB);
    unsigned short* tx = (unsigned short*)(ws + 2 * MATB);
    unsigned short* ty = (unsigned short*)(ws + 3 * MATB);
    (void)in_sizes; (void)n_in; (void)out_size; (void)ws_size;
    prep<<<dim3(1024), dim3(256), 0, stream>>>(x, y, fx, fy, tx, ty);
    biattn<<<dim3(1024), dim3(256), 0, stream>>>(
        x, y, fx, fy, tx, ty, (float*)d_out);
}